// Round 7
// baseline (203.460 us; speedup 1.0000x reference)
//
#include <hip/hip_runtime.h>
#include <math.h>

// LCAHeavyParentLoss: scalar = mean over [B,C] of BCE-with-logits(outputs,targets)
// + greedy-path parent cascade. B=2048, C=11110 (branching=10, depth=4).
//
// result = ( SUM_{B,C} [softplus(x) - x*t] + SUM_rows cascade ) / (B*C)
//
// R7: reads cap at ~3.2 TB/s through the VGPR-load path regardless of
// unroll/occupancy (R2-R6), while the fabric does 6.7 TB/s on writes.
// Switch streaming to the LDS-DMA path: global_load_lds width=16 (no VGPR
// destination -> nothing for regalloc to serialize; 8 x 1KB DMA per wave
// in flight), drain once per 32 KB window, compute from LDS.
// n4 = 5,688,320 = 1024 * 5555 windows exactly -> no tail.

#define BRANCH 10
#define DEPTH  4
#define C_COLS 11110
#define NBLK   1024
#define NTHR   256
#define WIN    1024            // float4 per window per matrix (16 KB)

typedef float vfloat4 __attribute__((ext_vector_type(4)));

#define ASYNC_LD16(gsrc, ldst)                                         \
    __builtin_amdgcn_global_load_lds(                                  \
        (__attribute__((address_space(1))) void*)(gsrc),               \
        (__attribute__((address_space(3))) void*)(ldst), 16, 0, 0)

__device__ __forceinline__ float softplus_fast(float x) {
    // softplus(x) = max(x,0) + ln2 * log2(1 + exp2(-|x|*log2e))
    float ax = __builtin_fabsf(x);
    float p  = __builtin_amdgcn_exp2f(-1.44269504f * ax);   // v_exp_f32
    float l  = __builtin_amdgcn_logf(1.0f + p);             // v_log_f32
    return __builtin_fmaxf(x, 0.0f) + 0.69314718f * l;
}

__device__ __forceinline__ float bce4(vfloat4 xv, vfloat4 tv) {
    float a = softplus_fast(xv.x) - xv.x * tv.x;
    float b = softplus_fast(xv.y) - xv.y * tv.y;
    float c = softplus_fast(xv.z) - xv.z * tv.z;
    float d = softplus_fast(xv.w) - xv.w * tv.w;
    return (a + b) + (c + d);
}

__global__ __launch_bounds__(NTHR) void bce_path_kernel(
    const float* __restrict__ x, const float* __restrict__ t,
    float* __restrict__ partials, int n4, int n_rows)
{
    const vfloat4* __restrict__ x4 = (const vfloat4*)x;
    const vfloat4* __restrict__ t4 = (const vfloat4*)t;

    __shared__ vfloat4 bx[WIN];   // 16 KB
    __shared__ vfloat4 bt[WIN];   // 16 KB

    const int gtid = blockIdx.x * blockDim.x + threadIdx.x;
    const int wave = threadIdx.x >> 6;
    const int lane = threadIdx.x & 63;

    float s0 = 0.0f, s1 = 0.0f, s2 = 0.0f, s3 = 0.0f;

    // --- path cascade: one row per global thread (first n_rows threads) ---
    if (gtid < n_rows) {
        const float* xr = x + (size_t)gtid * C_COLS;
        const float* tr = t + (size_t)gtid * C_COLS;
        int   e[DEPTH];
        float xv[DEPTH];
        int node = 0;
        #pragma unroll
        for (int l = 0; l < DEPTH; ++l) {
            int base = node * BRANCH;
            float best = xr[base];
            int   bi   = 0;
            #pragma unroll
            for (int c = 1; c < BRANCH; ++c) {
                float v = xr[base + c];
                if (v > best) { best = v; bi = c; }   // first-max, matches jnp.argmax
            }
            e[l]  = base + bi;
            xv[l] = best;
            node  = e[l] + 1;
        }
        float carry = 0.0f;
        #pragma unroll
        for (int l = DEPTH - 1; l >= 1; --l) {
            float addl = (tr[e[l]] == 0.0f) ? (softplus_fast(xv[l]) + carry) : 0.0f;
            s0   += addl;
            carry = addl;
        }
    }

    // --- main BCE sum: LDS-DMA staged windows (window-grid-stride) ---
    const int nwin = n4 / WIN;                    // 5555
    for (int win = blockIdx.x; win < nwin; win += NBLK) {
        const int base = win * WIN;
        // stage: 4 slots per matrix per wave, wave-uniform LDS base + lane*16
        #pragma unroll
        for (int k = 0; k < 4; ++k) {
            const int off = k * NTHR + wave * 64;           // wave-uniform
            ASYNC_LD16(x4 + base + off + lane, &bx[off]);
            ASYNC_LD16(t4 + base + off + lane, &bt[off]);
        }
        asm volatile("s_waitcnt vmcnt(0)" ::: "memory");
        __syncthreads();
        {
            vfloat4 a0 = bx[threadIdx.x];
            vfloat4 b0 = bt[threadIdx.x];
            vfloat4 a1 = bx[threadIdx.x + NTHR];
            vfloat4 b1 = bt[threadIdx.x + NTHR];
            vfloat4 a2 = bx[threadIdx.x + 2 * NTHR];
            vfloat4 b2 = bt[threadIdx.x + 2 * NTHR];
            vfloat4 a3 = bx[threadIdx.x + 3 * NTHR];
            vfloat4 b3 = bt[threadIdx.x + 3 * NTHR];
            s0 += bce4(a0, b0);
            s1 += bce4(a1, b1);
            s2 += bce4(a2, b2);
            s3 += bce4(a3, b3);
        }
        __syncthreads();   // buffer reuse guard
    }
    float s = (s0 + s1) + (s2 + s3);

    // wave64 reduce
    #pragma unroll
    for (int off = 32; off > 0; off >>= 1)
        s += __shfl_down(s, off, 64);
    __shared__ float wsum[NTHR / 64];
    if (lane == 0) wsum[wave] = s;
    __syncthreads();
    if (threadIdx.x == 0)
        partials[blockIdx.x] = (wsum[0] + wsum[1]) + (wsum[2] + wsum[3]);
}

__global__ __launch_bounds__(NTHR) void final_reduce_kernel(
    const float* __restrict__ partials, float* __restrict__ out, float inv_scale)
{
    const vfloat4* p4 = (const vfloat4*)partials;   // NBLK/4 float4
    float s = 0.0f;
    for (int i = threadIdx.x; i < NBLK / 4; i += NTHR) {
        vfloat4 v = p4[i];
        s += (v.x + v.y) + (v.z + v.w);
    }
    #pragma unroll
    for (int off = 32; off > 0; off >>= 1)
        s += __shfl_down(s, off, 64);
    __shared__ float wsum[NTHR / 64];
    int lane = threadIdx.x & 63;
    int wid  = threadIdx.x >> 6;
    if (lane == 0) wsum[wid] = s;
    __syncthreads();
    if (threadIdx.x == 0)
        out[0] = ((wsum[0] + wsum[1]) + (wsum[2] + wsum[3])) * inv_scale;
}

extern "C" void kernel_launch(void* const* d_in, const int* in_sizes, int n_in,
                              void* d_out, int out_size, void* d_ws, size_t ws_size,
                              hipStream_t stream) {
    const float* outputs = (const float*)d_in[0];
    const float* targets = (const float*)d_in[1];
    float* out      = (float*)d_out;
    float* partials = (float*)d_ws;               // NBLK floats

    const int total = in_sizes[0];                // B * C = 22,753,280
    const int B     = total / C_COLS;             // 2048
    const int n4    = total / 4;                  // 5,688,320 = 1024 * 5555
    const float inv = 1.0f / (float)total;

    bce_path_kernel<<<NBLK, NTHR, 0, stream>>>(outputs, targets, partials, n4, B);
    final_reduce_kernel<<<1, NTHR, 0, stream>>>(partials, out, inv);
}